// Round 13
// baseline (673.814 us; speedup 1.0000x reference)
//
#include <hip/hip_runtime.h>

// Problem constants (fixed by reference)
constexpr int B_ROWS = 65536;
constexpr int IN_F   = 1024;
constexpr int OUT_F  = 1024;

constexpr int BDIM = 256;            // 4 waves, 2M x 2N
constexpr int BM = 128, BN = 128, BK = 64;

typedef __bf16 bf16x8 __attribute__((ext_vector_type(8)));
typedef __bf16 bf16x4 __attribute__((ext_vector_type(4)));
typedef float  f32x4  __attribute__((ext_vector_type(4)));

__device__ __forceinline__ bf16x8 cvt8(f32x4 u0, f32x4 u1) {
    bf16x8 v;
    v[0] = (__bf16)u0[0]; v[1] = (__bf16)u0[1]; v[2] = (__bf16)u0[2]; v[3] = (__bf16)u0[3];
    v[4] = (__bf16)u1[0]; v[5] = (__bf16)u1[1]; v[6] = (__bf16)u1[2]; v[7] = (__bf16)u1[3];
    return v;
}

__device__ __forceinline__ bf16x4 cvt4(f32x4 a) {
    bf16x4 v;
    v[0] = (__bf16)a[0]; v[1] = (__bf16)a[1]; v[2] = (__bf16)a[2]; v[3] = (__bf16)a[3];
    return v;
}

// async global->LDS, 16B per lane (wave stages 1KB contiguous at uniform lds base)
__device__ __forceinline__ void glds16(const __bf16* g, unsigned char* l) {
    __builtin_amdgcn_global_load_lds(
        (const __attribute__((address_space(1))) unsigned int*)(const void*)g,
        (__attribute__((address_space(3))) unsigned int*)(void*)l,
        16, 0, 0);
}

// ---------------- f32 -> bf16 convert (r12; ~85us, at the mixed-stream rate) --------
__global__ __launch_bounds__(256)
void cvt_all(const float* __restrict__ X, const float* __restrict__ W,
             __bf16* __restrict__ Xb, __bf16* __restrict__ Wb) {
    const int b = blockIdx.x;
    const int t = threadIdx.x;
    if (b < 4096) {   // X: 16.78M f32x4 units, 16/thread, grid-stride
        size_t u = (size_t)b * 256 + t;
        const f32x4* __restrict__ xi = (const f32x4*)X;
        #pragma unroll 4
        for (int it = 0; it < 16; ++it, u += (size_t)4096 * 256) {
            f32x4 a = __builtin_nontemporal_load(xi + u);
            *(bf16x4*)(Xb + u * 4) = cvt4(a);
        }
    } else {          // W
        size_t u = (size_t)(b - 4096) * 256 + t;
        const f32x4* __restrict__ wi = (const f32x4*)W;
        #pragma unroll 4
        for (int it = 0; it < 4; ++it, u += (size_t)256 * 256) {
            f32x4 a = __builtin_nontemporal_load(wi + u);
            *(bf16x4*)(Wb + u * 4) = cvt4(a);
        }
    }
}

// ---------------- 128x128, BK=64, 4-wave, 2-phase/K-tile, 2 BLOCKS/CU ----------------
// r12's proven schedule scaled to half tile so LDS = 2 x 32KB = 64KB/block ->
// TWO independent blocks per CU (same 8 waves/CU, but two barrier domains: one
// block's MFMA fills the other's barrier/vmcnt/epilogue stalls — the overlap
// r8/r9's chaining failed to buy safely). Buffer (32KB): A kh0 [0,8K) kh1
// [8K,16K), B kh0 [16K,24K) kh1 [24K,32K); MFMA-order 1KB blocks (lane l: row
// 16bi+(l&15), k-seg (l>>4)*8, byte l*16). Wave w stages rows 32w..32w+31 of
// each operand (2 glds16 per quadrant). Round = 2 phases of {4 glds issue,
// 8 ds_reads, BAR, 16 MFMA (setprio), BAR}; end-of-round vmcnt(4) retires tile
// t+1 exactly, keeps (t+2)-kh0's 4 loads in flight (same invariant as r4/r12:
// carry-4 + P0-4 + P1-4 = 12 in flight, VM4 leaves 4).
// Ledger (do not revisit): r8/r9 chaining => 3x WRITE amplification; r11 B-in-
// regs => 257us; r5/r6/r7 in-GEMM f32 cvt => 285-330us; r12 cvt coalescing => null.
__global__ __launch_bounds__(BDIM, 2)
void fused_linear_act(const __bf16* __restrict__ Xb,  // [B_ROWS][IN_F] bf16
                      const __bf16* __restrict__ Wb,  // [OUT_F][IN_F] bf16
                      const float* __restrict__ bias, // [OUT_F]
                      float* __restrict__ O)          // [B_ROWS][OUT_F]
{
    __shared__ __attribute__((aligned(16))) unsigned char lds[2 * 32768];  // 64 KB

    const int bx  = blockIdx.x;                 // 4096 blocks
    // XCD-aware: 8 consecutive blocks per XCD share one A panel (L2 reuse).
    const int xcd = bx & 7;
    const int idx = bx >> 3;
    const int nt  = idx & 7;
    const int mt  = xcd + 8 * (idx >> 3);
    const int m0 = mt * BM;
    const int n0 = nt * BN;

    const int tid  = threadIdx.x;
    const int lane = tid & 63;
    const int wave = tid >> 6;                  // 0..3, 2M x 2N
    const int wr   = wave >> 1;
    const int wc   = wave & 1;
    const int lrow = lane & 15;
    const int quad = lane >> 4;

    // staging global sources (per-lane, MFMA-order pre-swizzle)
    const __bf16* agp = Xb + (size_t)(m0 + 32 * wave + lrow) * IN_F + quad * 8;
    const __bf16* bgp = Wb + (size_t)(n0 + 32 * wave + lrow) * IN_F + quad * 8;

    unsigned char* const b0 = lds;
    unsigned char* const b1 = lds + 32768;

    f32x4 acc[4][4];
    #pragma unroll
    for (int i = 0; i < 4; ++i)
        #pragma unroll
        for (int j = 0; j < 4; ++j)
            acc[i][j] = (f32x4){0.f, 0.f, 0.f, 0.f};

    bf16x8 aq0, aq1, aq2, aq3, bq0, bq1, bq2, bq3;

#define GA(BUF, KH, K) do { unsigned char* _d = (BUF) + (KH) * 8192 + wave * 2048; \
    glds16(agp + (K), _d); glds16(agp + (K) + 16 * IN_F, _d + 1024); } while (0)
#define GB(BUF, KH, K) do { unsigned char* _d = (BUF) + 16384 + (KH) * 8192 + wave * 2048; \
    glds16(bgp + (K), _d); glds16(bgp + (K) + 16 * IN_F, _d + 1024); } while (0)
#define RA(BUF, KH) do { \
    const unsigned char* _r = (BUF) + (KH) * 8192 + (wr * 4) * 1024 + lane * 16; \
    aq0 = *(const bf16x8*)(_r);        aq1 = *(const bf16x8*)(_r + 1024); \
    aq2 = *(const bf16x8*)(_r + 2048); aq3 = *(const bf16x8*)(_r + 3072); } while (0)
#define RB(BUF, KH) do { \
    const unsigned char* _r = (BUF) + 16384 + (KH) * 8192 + (wc * 4) * 1024 + lane * 16; \
    bq0 = *(const bf16x8*)(_r);        bq1 = *(const bf16x8*)(_r + 1024); \
    bq2 = *(const bf16x8*)(_r + 2048); bq3 = *(const bf16x8*)(_r + 3072); } while (0)
#define MFMA1(I, J) acc[I][J] = \
    __builtin_amdgcn_mfma_f32_16x16x32_bf16(aq##I, bq##J, acc[I][J], 0, 0, 0)
#define MFMAQ() do { __builtin_amdgcn_s_setprio(1); \
    MFMA1(0,0); MFMA1(0,1); MFMA1(0,2); MFMA1(0,3); \
    MFMA1(1,0); MFMA1(1,1); MFMA1(1,2); MFMA1(1,3); \
    MFMA1(2,0); MFMA1(2,1); MFMA1(2,2); MFMA1(2,3); \
    MFMA1(3,0); MFMA1(3,1); MFMA1(3,2); MFMA1(3,3); \
    __builtin_amdgcn_s_setprio(0); } while (0)
#define BAR() __builtin_amdgcn_s_barrier()
#define VM4() asm volatile("s_waitcnt vmcnt(4)" ::: "memory")
#define VM0() asm volatile("s_waitcnt vmcnt(0)" ::: "memory")

// Steady round KT (tile KT in CUR): P0 stages (KT+1)-kh1 -> OPP; P1 stages
// (KT+2)-kh0 -> CUR (kh0 region fully read at P0, barrier-protected).
#define SROUND(CUR, OPP, KT) do { \
    GA(OPP, 1, ((KT) + 1) * 64 + 32); GB(OPP, 1, ((KT) + 1) * 64 + 32); \
    RB(CUR, 0); RA(CUR, 0); BAR(); MFMAQ(); BAR(); \
    GA(CUR, 0, ((KT) + 2) * 64); GB(CUR, 0, ((KT) + 2) * 64); \
    RB(CUR, 1); RA(CUR, 1); BAR(); MFMAQ(); VM4(); BAR(); \
} while (0)

    // Prologue: tile0 fully staged into b0; tile1 kh0 into b1; retire tile0 only.
    GA(b0, 0, 0);  GB(b0, 0, 0);
    GA(b0, 1, 32); GB(b0, 1, 32);
    GA(b1, 0, 64); GB(b1, 0, 64);
    VM4();          // tile0's 8 retired; tile1-kh0's 4 stay in flight
    BAR();

    #pragma unroll 1
    for (int kt = 0; kt < 14; kt += 2) {
        SROUND(b0, b1, kt);
        SROUND(b1, b0, kt + 1);
    }
    // Round 14 (tile14 in b0): P0 stages tile15-kh1; then full drain.
    GA(b1, 1, 15 * 64 + 32); GB(b1, 1, 15 * 64 + 32);
    RB(b0, 0); RA(b0, 0); BAR(); MFMAQ(); BAR();
    RB(b0, 1); RA(b0, 1); BAR(); MFMAQ(); VM0(); BAR();
    // Round 15 (tile15 in b1): pure compute.
    RB(b1, 0); RA(b1, 0); BAR(); MFMAQ(); BAR();
    RB(b1, 1); RA(b1, 1); BAR(); MFMAQ();

    // Epilogue: bias + cyclic activation; selector = col%4 = lane&3 (branchless).
    // Normal stores (L2 merges 64B wave segments). With 2 blocks/CU, the other
    // block's K-loop hides this store burst.
    const int s = lane & 3;
    const float kmul = (s == 0) ? -2.f : -1.f;
    const float aa   = (s == 0) ?  2.f :  1.f;
    const float cc   = (s == 0) ? -1.f :  0.f;
    const bool  is_sin  = (s == 1);
    const bool  is_relu = (s == 2);

    float bv[4];
    #pragma unroll
    for (int fn = 0; fn < 4; ++fn) bv[fn] = bias[n0 + wc * 64 + fn * 16 + lrow];

    #pragma unroll
    for (int fm = 0; fm < 4; ++fm) {
        #pragma unroll
        for (int r = 0; r < 4; ++r) {
            const int gr = m0 + wr * 64 + fm * 16 + quad * 4 + r;
            float* op = O + (size_t)gr * OUT_F + n0 + wc * 64 + lrow;
            #pragma unroll
            for (int fn = 0; fn < 4; ++fn) {
                const float y = acc[fm][fn][r] + bv[fn];
                const float e = __expf(kmul * y);
                const float g = fmaf(aa, __builtin_amdgcn_rcpf(1.f + e), cc);
                const float sv = __sinf(y);
                const float rv = fmaxf(y, 0.f);
                const float res = is_sin ? sv : (is_relu ? rv : g);
                op[fn * 16] = res;
            }
        }
    }
}

// ================= fallback (ws too small for Xb): r12 reg-staged fused 256^2 ========
__global__ __launch_bounds__(256)
void w_to_bf16(const float* __restrict__ W, __bf16* __restrict__ Wb) {
    const size_t i = ((size_t)blockIdx.x * 256 + threadIdx.x) * 16;
    f32x4 a0 = *(const f32x4*)(W + i);
    f32x4 a1 = *(const f32x4*)(W + i + 4);
    f32x4 a2 = *(const f32x4*)(W + i + 8);
    f32x4 a3 = *(const f32x4*)(W + i + 12);
    *(bf16x8*)(Wb + i)     = cvt8(a0, a1);
    *(bf16x8*)(Wb + i + 8) = cvt8(a2, a3);
}

__global__ __launch_bounds__(512, 2)
void fused_fallback(const float* __restrict__ X, const __bf16* __restrict__ Wb,
                    const float* __restrict__ bias, float* __restrict__ O)
{
    __shared__ __attribute__((aligned(16))) unsigned char lds[2 * 65536];
    const int bx  = blockIdx.x;
    const int xcd = bx & 7;
    const int idx = bx >> 3;
    const int nt  = idx & 3;
    const int mt  = xcd + 8 * (idx >> 2);
    const int m0 = mt * 256;
    const int n0 = nt * 256;
    const int tid  = threadIdx.x;
    const int lane = tid & 63;
    const int wave = tid >> 6;
    const int wr2  = wave >> 2;
    const int w4   = wave & 3;
    const int lrow = lane & 15;
    const int quad = lane >> 4;
    const int arow = tid >> 1;
    const int ah   = tid & 1;
    const float* asrc = X + (size_t)(m0 + arow) * IN_F + ah * 32;
    const int awr = ah * 16384 + (arow >> 4) * 1024 + (arow & 15) * 16;
    const __bf16* bgp = Wb + (size_t)(n0 + 32 * wave + lrow) * IN_F + quad * 8;
    unsigned char* const b0 = lds;
    unsigned char* const b1 = lds + 65536;
    f32x4 acc[8][4];
    #pragma unroll
    for (int i = 0; i < 8; ++i)
        #pragma unroll
        for (int j = 0; j < 4; ++j)
            acc[i][j] = (f32x4){0.f, 0.f, 0.f, 0.f};
    f32x4 ar0, ar1, ar2, ar3, ar4, ar5, ar6, ar7;
    bf16x8 aq0, aq1, aq2, aq3, bq0, bq1, bq2, bq3;
#define FRA(BUF, KH, MH) do { \
    const unsigned char* _r = (BUF) + (KH) * 16384 + (wr2 * 8 + (MH) * 4) * 1024 + lane * 16; \
    aq0 = *(const bf16x8*)(_r);        aq1 = *(const bf16x8*)(_r + 1024); \
    aq2 = *(const bf16x8*)(_r + 2048); aq3 = *(const bf16x8*)(_r + 3072); } while (0)
#define FRB(BUF, KH) do { \
    const unsigned char* _r = (BUF) + 32768 + (KH) * 16384 + (w4 * 4) * 1024 + lane * 16; \
    bq0 = *(const bf16x8*)(_r);        bq1 = *(const bf16x8*)(_r + 1024); \
    bq2 = *(const bf16x8*)(_r + 2048); bq3 = *(const bf16x8*)(_r + 3072); } while (0)
#define FMFMA1(MH, I, J) acc[(MH)*4+(I)][(J)] = \
    __builtin_amdgcn_mfma_f32_16x16x32_bf16(aq##I, bq##J, acc[(MH)*4+(I)][(J)], 0, 0, 0)
#define FMFMAQ(MH) do { __builtin_amdgcn_s_setprio(1); \
    FMFMA1(MH,0,0); FMFMA1(MH,0,1); FMFMA1(MH,0,2); FMFMA1(MH,0,3); \
    FMFMA1(MH,1,0); FMFMA1(MH,1,1); FMFMA1(MH,1,2); FMFMA1(MH,1,3); \
    FMFMA1(MH,2,0); FMFMA1(MH,2,1); FMFMA1(MH,2,2); FMFMA1(MH,2,3); \
    FMFMA1(MH,3,0); FMFMA1(MH,3,1); FMFMA1(MH,3,2); FMFMA1(MH,3,3); \
    __builtin_amdgcn_s_setprio(0); } while (0)
#define ALOAD(KA) do { \
    ar0 = *(const f32x4*)(asrc + (KA));      ar1 = *(const f32x4*)(asrc + (KA) + 4);  \
    ar2 = *(const f32x4*)(asrc + (KA) + 8);  ar3 = *(const f32x4*)(asrc + (KA) + 12); \
    ar4 = *(const f32x4*)(asrc + (KA) + 16); ar5 = *(const f32x4*)(asrc + (KA) + 20); \
    ar6 = *(const f32x4*)(asrc + (KA) + 24); ar7 = *(const f32x4*)(asrc + (KA) + 28); } while (0)
#define DSW(BUF) do { unsigned char* _w = (BUF) + awr; \
    *(bf16x8*)(_w)       = cvt8(ar0, ar1); \
    *(bf16x8*)(_w + 256) = cvt8(ar2, ar3); \
    *(bf16x8*)(_w + 512) = cvt8(ar4, ar5); \
    *(bf16x8*)(_w + 768) = cvt8(ar6, ar7); } while (0)
#define GBALL(BUF, K) do { unsigned char* _d0 = (BUF) + 32768 + wave * 2048; \
    unsigned char* _d1 = _d0 + 16384; \
    glds16(bgp + (K), _d0);      glds16(bgp + (K) + 16 * IN_F, _d0 + 1024); \
    glds16(bgp + (K) + 32, _d1); glds16(bgp + (K) + 32 + 16 * IN_F, _d1 + 1024); } while (0)
#define FROUND(CUR, OPP, DO_STAGE, KB1, DO_ALOAD, KA2, VMW) do { \
    if (DO_STAGE) { GBALL(OPP, KB1); DSW(OPP); } \
    if (DO_ALOAD) { ALOAD(KA2); __builtin_amdgcn_sched_barrier(0); } \
    FRB(CUR, 0); FRA(CUR, 0, 0); BAR(); FMFMAQ(0); BAR(); \
    FRA(CUR, 0, 1); BAR(); FMFMAQ(1); BAR(); \
    FRB(CUR, 1); FRA(CUR, 1, 0); BAR(); FMFMAQ(0); BAR(); \
    FRA(CUR, 1, 1); BAR(); FMFMAQ(1); VMW; BAR(); \
} while (0)
    ALOAD(0);
    GBALL(b0, 0);
    DSW(b0);
    ALOAD(64);
    asm volatile("s_waitcnt vmcnt(8) lgkmcnt(0)" ::: "memory");
    BAR();
    #pragma unroll 1
    for (int t = 0; t < 14; t += 2) {
        FROUND(b0, b1, true, (t + 1) * 64, true, (t + 2) * 64, asm volatile("s_waitcnt vmcnt(8)" ::: "memory"));
        FROUND(b1, b0, true, (t + 2) * 64, true, (t + 3) * 64, asm volatile("s_waitcnt vmcnt(8)" ::: "memory"));
    }
    FROUND(b0, b1, true, 15 * 64, false, 0, VM0());
    FROUND(b1, b0, false, 0, false, 0, (void)0);
    const int s = lane & 3;
    const float kmul = (s == 0) ? -2.f : -1.f;
    const float aa   = (s == 0) ?  2.f :  1.f;
    const float cc   = (s == 0) ? -1.f :  0.f;
    const bool  is_sin  = (s == 1);
    const bool  is_relu = (s == 2);
    float bv[4];
    #pragma unroll
    for (int fn = 0; fn < 4; ++fn) bv[fn] = bias[n0 + w4 * 64 + fn * 16 + lrow];
    #pragma unroll
    for (int fm = 0; fm < 8; ++fm) {
        #pragma unroll
        for (int r = 0; r < 4; ++r) {
            const int gr = m0 + wr2 * 128 + fm * 16 + quad * 4 + r;
            float* op = O + (size_t)gr * OUT_F + n0 + w4 * 64 + lrow;
            #pragma unroll
            for (int fn = 0; fn < 4; ++fn) {
                const float y = acc[fm][fn][r] + bv[fn];
                const float e = __expf(kmul * y);
                const float gg = fmaf(aa, __builtin_amdgcn_rcpf(1.f + e), cc);
                const float sv = __sinf(y);
                const float rv = fmaxf(y, 0.f);
                const float res = is_sin ? sv : (is_relu ? rv : gg);
                op[fn * 16] = res;
            }
        }
    }
}

extern "C" void kernel_launch(void* const* d_in, const int* in_sizes, int n_in,
                              void* d_out, int out_size, void* d_ws, size_t ws_size,
                              hipStream_t stream) {
    const float* X = (const float*)d_in[0];
    const float* W = (const float*)d_in[1];
    const float* b = (const float*)d_in[2];
    float* O = (float*)d_out;

    const size_t nX = (size_t)B_ROWS * IN_F;
    const size_t nW = (size_t)OUT_F * IN_F;

    if (ws_size >= (nW + nX) * sizeof(__bf16)) {
        __bf16* Wb = (__bf16*)d_ws;
        __bf16* Xb = (__bf16*)d_ws + nW;
        cvt_all<<<4096 + 256, 256, 0, stream>>>(X, W, Xb, Wb);
        const int grid = (B_ROWS / BM) * (OUT_F / BN);  // 4096 blocks
        fused_linear_act<<<grid, BDIM, 0, stream>>>(Xb, Wb, b, O);
    } else {
        __bf16* Wb = (__bf16*)d_ws;   // 2 MB
        w_to_bf16<<<(int)(nW / (256 * 16)), 256, 0, stream>>>(W, Wb);
        fused_fallback<<<(B_ROWS / 256) * (OUT_F / 256), 512, 0, stream>>>(X, Wb, b, O);
    }
}

// Round 14
// 579.967 us; speedup vs baseline: 1.1618x; 1.1618x over previous
//
#include <hip/hip_runtime.h>

// Problem constants (fixed by reference)
constexpr int B_ROWS = 65536;
constexpr int IN_F   = 1024;
constexpr int OUT_F  = 1024;

constexpr int BDIM = 512;            // 8 waves, 2M x 4N
constexpr int BM = 256, BN = 256, BK = 64;

typedef __bf16 bf16x8 __attribute__((ext_vector_type(8)));
typedef __bf16 bf16x4 __attribute__((ext_vector_type(4)));
typedef float  f32x4  __attribute__((ext_vector_type(4)));

__device__ __forceinline__ bf16x8 cvt8(f32x4 u0, f32x4 u1) {
    bf16x8 v;
    v[0] = (__bf16)u0[0]; v[1] = (__bf16)u0[1]; v[2] = (__bf16)u0[2]; v[3] = (__bf16)u0[3];
    v[4] = (__bf16)u1[0]; v[5] = (__bf16)u1[1]; v[6] = (__bf16)u1[2]; v[7] = (__bf16)u1[3];
    return v;
}

__device__ __forceinline__ bf16x4 cvt4(f32x4 a) {
    bf16x4 v;
    v[0] = (__bf16)a[0]; v[1] = (__bf16)a[1]; v[2] = (__bf16)a[2]; v[3] = (__bf16)a[3];
    return v;
}

// async global->LDS, 16B per lane (wave stages 1KB contiguous at uniform lds base)
__device__ __forceinline__ void glds16(const __bf16* g, unsigned char* l) {
    __builtin_amdgcn_global_load_lds(
        (const __attribute__((address_space(1))) unsigned int*)(const void*)g,
        (__attribute__((address_space(3))) unsigned int*)(void*)l,
        16, 0, 0);
}

// ---------------- f32 -> bf16 convert (~85us; at the chip's mixed-stream rate) ------
// nt loads: dead-after-read X must not evict Xb/Wb from L3. Cached stores: Xb
// must stay L3-hot for the GEMM (FETCH=98MB < Xb's 128MB proves it works).
__global__ __launch_bounds__(256)
void cvt_all(const float* __restrict__ X, const float* __restrict__ W,
             __bf16* __restrict__ Xb, __bf16* __restrict__ Wb) {
    const int b = blockIdx.x;
    const int t = threadIdx.x;
    if (b < 4096) {   // X: 16.78M f32x4 units, 16/thread, grid-stride
        size_t u = (size_t)b * 256 + t;
        const f32x4* __restrict__ xi = (const f32x4*)X;
        #pragma unroll 4
        for (int it = 0; it < 16; ++it, u += (size_t)4096 * 256) {
            f32x4 a = __builtin_nontemporal_load(xi + u);
            *(bf16x4*)(Xb + u * 4) = cvt4(a);
        }
    } else {          // W
        size_t u = (size_t)(b - 4096) * 256 + t;
        const f32x4* __restrict__ wi = (const f32x4*)W;
        #pragma unroll 4
        for (int it = 0; it < 4; ++it, u += (size_t)256 * 256) {
            f32x4 a = __builtin_nontemporal_load(wi + u);
            *(bf16x4*)(Wb + u * 4) = cvt4(a);
        }
    }
}

// ---------------- 256x256, BK=64, 8-wave, 4-phase/K-tile GEMM (proven best) ----------
// Grid 1024, one tile per block. Measured 195us (x2 sessions), MfmaUtil 30%,
// WRITE 262MB, FETCH 98MB, 0 bank conflicts. LDS buffer (64KB): A kh0/kh1
// [0,32K), B [32K,64K), MFMA-order 1KB blocks (lane l: row 16bi+(l&15), k-seg
// (l>>4)*8, byte l*16). Wave w stages blocks {2w,2w+1}/quadrant via 2 glds16.
// Per phase: glds issue, ds_reads, BAR, 16 MFMA (setprio), BAR. End-of-round
// vmcnt(4) retires tile t+1 fully, keeps tile t+2's kh0 in flight.
// Session ledger — structural alternatives ALL measured worse (do not revisit):
//  r5/r6 fused reg-staged f32 A: 284-333 | r7 f32-A-in-LDS BK32: 288
//  r8/r9 M-tile chaining: 362-384 (3x WRITE amplification)
//  r11 B-in-registers (1 barrier/round): 257 | r13 128^2 2-blocks/CU: 298
//  r12 cvt coalescing rewrite: null (~85us is the mixed-stream rate)
__global__ __launch_bounds__(BDIM, 2)
void fused_linear_act(const __bf16* __restrict__ Xb,  // [B_ROWS][IN_F] bf16
                      const __bf16* __restrict__ Wb,  // [OUT_F][IN_F] bf16
                      const float* __restrict__ bias, // [OUT_F]
                      float* __restrict__ O)          // [B_ROWS][OUT_F]
{
    __shared__ __attribute__((aligned(16))) unsigned char lds[2 * 65536];  // 128 KB

    const int bx  = blockIdx.x;                 // 1024 blocks
    // XCD-aware: 4 consecutive blocks per XCD share one A panel (L2 reuse).
    const int xcd = bx & 7;
    const int idx = bx >> 3;
    const int nt  = idx & 3;
    const int mt  = xcd + 8 * (idx >> 2);
    const int m0 = mt * BM;
    const int n0 = nt * BN;

    const int tid  = threadIdx.x;
    const int lane = tid & 63;
    const int wave = tid >> 6;                  // 0..7, 2M x 4N
    const int wr2  = wave >> 2;
    const int w4   = wave & 3;
    const int lrow = lane & 15;
    const int quad = lane >> 4;

    // staging global sources (per-lane, MFMA-order pre-swizzle)
    const __bf16* agp = Xb + (size_t)(m0 + 32 * wave + lrow) * IN_F + quad * 8;
    const __bf16* bgp = Wb + (size_t)(n0 + 32 * wave + lrow) * IN_F + quad * 8;

    unsigned char* const b0 = lds;
    unsigned char* const b1 = lds + 65536;

    f32x4 acc[8][4];
    #pragma unroll
    for (int i = 0; i < 8; ++i)
        #pragma unroll
        for (int j = 0; j < 4; ++j)
            acc[i][j] = (f32x4){0.f, 0.f, 0.f, 0.f};

    bf16x8 aq0, aq1, aq2, aq3, bq0, bq1, bq2, bq3;

#define GA(BUF, KH, K) do { unsigned char* _d = (BUF) + (KH) * 16384 + wave * 2048; \
    glds16(agp + (K), _d); glds16(agp + (K) + 16 * IN_F, _d + 1024); } while (0)
#define GB(BUF, KH, K) do { unsigned char* _d = (BUF) + 32768 + (KH) * 16384 + wave * 2048; \
    glds16(bgp + (K), _d); glds16(bgp + (K) + 16 * IN_F, _d + 1024); } while (0)
#define RA(BUF, KH, MH) do { \
    const unsigned char* _r = (BUF) + (KH) * 16384 + (wr2 * 8 + (MH) * 4) * 1024 + lane * 16; \
    aq0 = *(const bf16x8*)(_r);        aq1 = *(const bf16x8*)(_r + 1024); \
    aq2 = *(const bf16x8*)(_r + 2048); aq3 = *(const bf16x8*)(_r + 3072); } while (0)
#define RB(BUF, KH) do { \
    const unsigned char* _r = (BUF) + 32768 + (KH) * 16384 + (w4 * 4) * 1024 + lane * 16; \
    bq0 = *(const bf16x8*)(_r);        bq1 = *(const bf16x8*)(_r + 1024); \
    bq2 = *(const bf16x8*)(_r + 2048); bq3 = *(const bf16x8*)(_r + 3072); } while (0)
#define MFMA1(MH, I, J) acc[(MH)*4+(I)][(J)] = \
    __builtin_amdgcn_mfma_f32_16x16x32_bf16(aq##I, bq##J, acc[(MH)*4+(I)][(J)], 0, 0, 0)
#define MFMAQ(MH) do { __builtin_amdgcn_s_setprio(1); \
    MFMA1(MH,0,0); MFMA1(MH,0,1); MFMA1(MH,0,2); MFMA1(MH,0,3); \
    MFMA1(MH,1,0); MFMA1(MH,1,1); MFMA1(MH,1,2); MFMA1(MH,1,3); \
    MFMA1(MH,2,0); MFMA1(MH,2,1); MFMA1(MH,2,2); MFMA1(MH,2,3); \
    MFMA1(MH,3,0); MFMA1(MH,3,1); MFMA1(MH,3,2); MFMA1(MH,3,3); \
    __builtin_amdgcn_s_setprio(0); } while (0)
#define BAR() __builtin_amdgcn_s_barrier()
#define VM4() asm volatile("s_waitcnt vmcnt(4)" ::: "memory")
#define VM0() asm volatile("s_waitcnt vmcnt(0)" ::: "memory")

// Steady round KT (tile KT in CUR): stage (KT+1)-kh1 -> OPP, (KT+2)-kh0 -> CUR.
#define SROUND(CUR, OPP, KT) do { \
    GA(OPP, 1, ((KT) + 1) * 64 + 32); RB(CUR, 0); RA(CUR, 0, 0); \
             BAR(); MFMAQ(0); BAR(); \
    GB(OPP, 1, ((KT) + 1) * 64 + 32); RA(CUR, 0, 1); \
             BAR(); MFMAQ(1); BAR(); \
    GA(CUR, 0, ((KT) + 2) * 64); RB(CUR, 1); RA(CUR, 1, 0); \
             BAR(); MFMAQ(0); BAR(); \
    GB(CUR, 0, ((KT) + 2) * 64); RA(CUR, 1, 1); \
             BAR(); MFMAQ(1); VM4(); BAR(); \
} while (0)

    // Prologue: tile0 fully staged into b0; tile1 kh0 into b1; retire tile0 only.
    GA(b0, 0, 0);  GB(b0, 0, 0);
    GA(b0, 1, 32); GB(b0, 1, 32);
    GA(b1, 0, 64); GB(b1, 0, 64);
    VM4();          // tile0's 8 retired; tile1-kh0's 4 stay in flight
    BAR();

    #pragma unroll 1
    for (int kt = 0; kt < 14; kt += 2) {
        SROUND(b0, b1, kt);
        SROUND(b1, b0, kt + 1);
    }
    // Round 14 (tile14 in b0): stage tile15 kh1; no tile16 -> drain at end.
    GA(b1, 1, 15 * 64 + 32); RB(b0, 0); RA(b0, 0, 0); BAR(); MFMAQ(0); BAR();
    GB(b1, 1, 15 * 64 + 32); RA(b0, 0, 1);            BAR(); MFMAQ(1); BAR();
    RB(b0, 1); RA(b0, 1, 0);                          BAR(); MFMAQ(0); BAR();
    RA(b0, 1, 1);                                     BAR(); MFMAQ(1); VM0(); BAR();
    // Round 15 (tile15 in b1): pure compute.
    RB(b1, 0); RA(b1, 0, 0); BAR(); MFMAQ(0); BAR();
    RA(b1, 0, 1);            BAR(); MFMAQ(1); BAR();
    RB(b1, 1); RA(b1, 1, 0); BAR(); MFMAQ(0); BAR();
    RA(b1, 1, 1);            BAR(); MFMAQ(1);

    // Epilogue: bias + cyclic activation; selector = col%4 = lane&3 (branchless).
    // Normal stores — L2 merges the 64B wave segments (WRITE = 262MB proven).
    const int s = lane & 3;
    const float kmul = (s == 0) ? -2.f : -1.f;
    const float aa   = (s == 0) ?  2.f :  1.f;
    const float cc   = (s == 0) ? -1.f :  0.f;
    const bool  is_sin  = (s == 1);
    const bool  is_relu = (s == 2);

    float bv[4];
    #pragma unroll
    for (int fn = 0; fn < 4; ++fn) bv[fn] = bias[n0 + w4 * 64 + fn * 16 + lrow];

    #pragma unroll
    for (int fm = 0; fm < 8; ++fm) {
        #pragma unroll
        for (int r = 0; r < 4; ++r) {
            const int gr = m0 + wr2 * 128 + fm * 16 + quad * 4 + r;
            float* op = O + (size_t)gr * OUT_F + n0 + w4 * 64 + lrow;
            #pragma unroll
            for (int fn = 0; fn < 4; ++fn) {
                const float y = acc[fm][fn][r] + bv[fn];
                const float e = __expf(kmul * y);
                const float g = fmaf(aa, __builtin_amdgcn_rcpf(1.f + e), cc);
                const float sv = __sinf(y);
                const float rv = fmaxf(y, 0.f);
                const float res = is_sin ? sv : (is_relu ? rv : g);
                op[fn * 16] = res;
            }
        }
    }
}

// ================= fallback (ws too small for Xb): reg-staged fused kernel ===========
__global__ __launch_bounds__(256)
void w_to_bf16(const float* __restrict__ W, __bf16* __restrict__ Wb) {
    const size_t i = ((size_t)blockIdx.x * 256 + threadIdx.x) * 16;
    f32x4 a0 = *(const f32x4*)(W + i);
    f32x4 a1 = *(const f32x4*)(W + i + 4);
    f32x4 a2 = *(const f32x4*)(W + i + 8);
    f32x4 a3 = *(const f32x4*)(W + i + 12);
    *(bf16x8*)(Wb + i)     = cvt8(a0, a1);
    *(bf16x8*)(Wb + i + 8) = cvt8(a2, a3);
}

__global__ __launch_bounds__(BDIM, 2)
void fused_fallback(const float* __restrict__ X, const __bf16* __restrict__ Wb,
                    const float* __restrict__ bias, float* __restrict__ O)
{
    __shared__ __attribute__((aligned(16))) unsigned char lds[2 * 65536];
    const int bx  = blockIdx.x;
    const int xcd = bx & 7;
    const int idx = bx >> 3;
    const int nt  = idx & 3;
    const int mt  = xcd + 8 * (idx >> 2);
    const int m0 = mt * BM;
    const int n0 = nt * BN;
    const int tid  = threadIdx.x;
    const int lane = tid & 63;
    const int wave = tid >> 6;
    const int wr2  = wave >> 2;
    const int w4   = wave & 3;
    const int lrow = lane & 15;
    const int quad = lane >> 4;
    const int arow = tid >> 1;
    const int ah   = tid & 1;
    const float* asrc = X + (size_t)(m0 + arow) * IN_F + ah * 32;
    const int awr = ah * 16384 + (arow >> 4) * 1024 + (arow & 15) * 16;
    const __bf16* bgp = Wb + (size_t)(n0 + 32 * wave + lrow) * IN_F + quad * 8;
    unsigned char* const b0 = lds;
    unsigned char* const b1 = lds + 65536;
    f32x4 acc[8][4];
    #pragma unroll
    for (int i = 0; i < 8; ++i)
        #pragma unroll
        for (int j = 0; j < 4; ++j)
            acc[i][j] = (f32x4){0.f, 0.f, 0.f, 0.f};
    f32x4 ar0, ar1, ar2, ar3, ar4, ar5, ar6, ar7;
    bf16x8 aq0, aq1, aq2, aq3, bq0, bq1, bq2, bq3;
#define ALOAD(KA) do { \
    ar0 = *(const f32x4*)(asrc + (KA));      ar1 = *(const f32x4*)(asrc + (KA) + 4);  \
    ar2 = *(const f32x4*)(asrc + (KA) + 8);  ar3 = *(const f32x4*)(asrc + (KA) + 12); \
    ar4 = *(const f32x4*)(asrc + (KA) + 16); ar5 = *(const f32x4*)(asrc + (KA) + 20); \
    ar6 = *(const f32x4*)(asrc + (KA) + 24); ar7 = *(const f32x4*)(asrc + (KA) + 28); } while (0)
#define DSW(BUF) do { unsigned char* _w = (BUF) + awr; \
    *(bf16x8*)(_w)       = cvt8(ar0, ar1); \
    *(bf16x8*)(_w + 256) = cvt8(ar2, ar3); \
    *(bf16x8*)(_w + 512) = cvt8(ar4, ar5); \
    *(bf16x8*)(_w + 768) = cvt8(ar6, ar7); } while (0)
#define GBALL(BUF, K) do { unsigned char* _d0 = (BUF) + 32768 + wave * 2048; \
    unsigned char* _d1 = _d0 + 16384; \
    glds16(bgp + (K), _d0);      glds16(bgp + (K) + 16 * IN_F, _d0 + 1024); \
    glds16(bgp + (K) + 32, _d1); glds16(bgp + (K) + 32 + 16 * IN_F, _d1 + 1024); } while (0)
#define FROUND(CUR, OPP, DO_STAGE, KB1, DO_ALOAD, KA2, VMW) do { \
    if (DO_STAGE) { GBALL(OPP, KB1); DSW(OPP); } \
    if (DO_ALOAD) { ALOAD(KA2); __builtin_amdgcn_sched_barrier(0); } \
    RB(CUR, 0); RA(CUR, 0, 0); BAR(); MFMAQ(0); BAR(); \
    RA(CUR, 0, 1); BAR(); MFMAQ(1); BAR(); \
    RB(CUR, 1); RA(CUR, 1, 0); BAR(); MFMAQ(0); BAR(); \
    RA(CUR, 1, 1); BAR(); MFMAQ(1); VMW; BAR(); \
} while (0)
    ALOAD(0);
    GBALL(b0, 0);
    DSW(b0);
    ALOAD(64);
    asm volatile("s_waitcnt vmcnt(8) lgkmcnt(0)" ::: "memory");
    BAR();
    #pragma unroll 1
    for (int t = 0; t < 14; t += 2) {
        FROUND(b0, b1, true, (t + 1) * 64, true, (t + 2) * 64, asm volatile("s_waitcnt vmcnt(8)" ::: "memory"));
        FROUND(b1, b0, true, (t + 2) * 64, true, (t + 3) * 64, asm volatile("s_waitcnt vmcnt(8)" ::: "memory"));
    }
    FROUND(b0, b1, true, 15 * 64, false, 0, VM0());
    FROUND(b1, b0, false, 0, false, 0, (void)0);
    const int s = lane & 3;
    const float kmul = (s == 0) ? -2.f : -1.f;
    const float aa   = (s == 0) ?  2.f :  1.f;
    const float cc   = (s == 0) ? -1.f :  0.f;
    const bool  is_sin  = (s == 1);
    const bool  is_relu = (s == 2);
    float bv[4];
    #pragma unroll
    for (int fn = 0; fn < 4; ++fn) bv[fn] = bias[n0 + w4 * 64 + fn * 16 + lrow];
    #pragma unroll
    for (int fm = 0; fm < 8; ++fm) {
        #pragma unroll
        for (int r = 0; r < 4; ++r) {
            const int gr = m0 + wr2 * 128 + fm * 16 + quad * 4 + r;
            float* op = O + (size_t)gr * OUT_F + n0 + w4 * 64 + lrow;
            #pragma unroll
            for (int fn = 0; fn < 4; ++fn) {
                const float y = acc[fm][fn][r] + bv[fn];
                const float e = __expf(kmul * y);
                const float gg = fmaf(aa, __builtin_amdgcn_rcpf(1.f + e), cc);
                const float sv = __sinf(y);
                const float rv = fmaxf(y, 0.f);
                const float res = is_sin ? sv : (is_relu ? rv : gg);
                op[fn * 16] = res;
            }
        }
    }
}

extern "C" void kernel_launch(void* const* d_in, const int* in_sizes, int n_in,
                              void* d_out, int out_size, void* d_ws, size_t ws_size,
                              hipStream_t stream) {
    const float* X = (const float*)d_in[0];
    const float* W = (const float*)d_in[1];
    const float* b = (const float*)d_in[2];
    float* O = (float*)d_out;

    const size_t nX = (size_t)B_ROWS * IN_F;
    const size_t nW = (size_t)OUT_F * IN_F;
    const int grid = (B_ROWS / BM) * (OUT_F / BN);  // 1024 blocks

    if (ws_size >= (nW + nX) * sizeof(__bf16)) {
        __bf16* Wb = (__bf16*)d_ws;
        __bf16* Xb = (__bf16*)d_ws + nW;
        cvt_all<<<4096 + 256, 256, 0, stream>>>(X, W, Xb, Wb);
        fused_linear_act<<<grid, BDIM, 0, stream>>>(Xb, Wb, b, O);
    } else {
        __bf16* Wb = (__bf16*)d_ws;   // 2 MB
        w_to_bf16<<<(int)(nW / (256 * 16)), 256, 0, stream>>>(W, Wb);
        fused_fallback<<<grid, BDIM, 0, stream>>>(X, Wb, b, O);
    }
}